// Round 8
// baseline (353.287 us; speedup 1.0000x reference)
//
#include <hip/hip_runtime.h>
#include <hip/hip_fp16.h>
#include <float.h>
#include <math.h>

#define D_IN 32
#define D_MAIN 128
#define D_BLOCK 256
#define CTX 96
#define LN_EPS 1e-5f

typedef _Float16 f16x8 __attribute__((ext_vector_type(8)));
typedef float f32x4 __attribute__((ext_vector_type(4)));
typedef unsigned short ushort4v __attribute__((ext_vector_type(4)));
typedef unsigned short ushort8v __attribute__((ext_vector_type(8)));

// f32 -> f16 bits: single v_cvt_f16_f32 (RNE).
__device__ __forceinline__ unsigned short f2h(float x) {
  return __half_as_ushort(__float2half(x));
}
__device__ __forceinline__ float h2f(unsigned short u) {
  return __half2float(__ushort_as_half(u));
}

// ---------------------------------------------------------------------------
// Combined: zero ghist/scount + pack all 8 weight matrices (fp16, MFMA
// B-fragment order). frag f = j*(K/32)+s ; lane l holds
// B[k=32s+(l>>4)*8+jj][n=16j+(l&15)]
// ---------------------------------------------------------------------------
struct PackJobs {
  const float* W[8];
  unsigned short* out[8];
  int K[8];
  int N[8];
  int cum[9];
};

__global__ __launch_bounds__(256) void prep_kernel(
    PackJobs pj, int* __restrict__ ghist, int na, int* __restrict__ scount, int nb)
{
  const int tid = blockIdx.x * 256 + threadIdx.x;
  if (tid < na) ghist[tid] = 0;
  else if (tid - na < nb) scount[tid - na] = 0;
  if (tid >= pj.cum[8]) return;
  int j = 0;
#pragma unroll
  for (int i = 1; i < 8; ++i)
    if (tid >= pj.cum[i]) j = i;
  const int lt = tid - pj.cum[j];
  const int K = pj.K[j], N = pj.N[j];
  const float* __restrict__ W = pj.W[j];
  const int l = lt & 63, f = lt >> 6;
  const int ks = K / 32;
  const int s = f % ks, jb = f / ks;
  const int kb = s * 32 + (l >> 4) * 8;
  const int n = jb * 16 + (l & 15);
  unsigned short v[8];
#pragma unroll
  for (int e = 0; e < 8; ++e) v[e] = f2h(W[(size_t)(kb + e) * N + n]);
  ushort4v* o = (ushort4v*)(pj.out[j] + (size_t)lt * 8);
  ushort4v u0 = {v[0], v[1], v[2], v[3]};
  ushort4v u1 = {v[4], v[5], v[6], v[7]};
  o[0] = u0; o[1] = u1;
}

// ---------------------------------------------------------------------------
// 128-row MFMA MLP block — used by tmod only. B-fragments hoisted into
// registers (GEMM2's issued BEFORE the barrier so L2 latency hides under the
// Us store + barrier). tmod runs at cap 256 VGPR — no spill.
// ---------------------------------------------------------------------------
#define LDA 136
#define LDU 72

__device__ __forceinline__ void mlp_block(
    f32x4 (&h)[4][4], unsigned short* __restrict__ As, unsigned short* __restrict__ Us,
    const unsigned short* __restrict__ W1_pk, const float* __restrict__ b1,
    const unsigned short* __restrict__ W2_pk, const float* __restrict__ b2,
    int mrow, int nw, int c, int q, int lane)
{
#pragma unroll 1
  for (int ch = 0; ch < 4; ++ch) {
    // GEMM1 B-frags upfront (8 frags = 32 VGPR)
    f16x8 b1f[4][2];
#pragma unroll
    for (int s = 0; s < 4; ++s)
#pragma unroll
      for (int ntl = 0; ntl < 2; ++ntl) {
        const int j = ch*4 + nw*2 + ntl;
        b1f[s][ntl] = *(const f16x8*)&W1_pk[((size_t)(j*4 + s) * 64 + lane) * 8];
      }
    f32x4 u[4][2];
#pragma unroll
    for (int mi = 0; mi < 4; ++mi)
#pragma unroll
      for (int ntl = 0; ntl < 2; ++ntl) { f32x4 z = {0.f,0.f,0.f,0.f}; u[mi][ntl] = z; }
#pragma unroll
    for (int s = 0; s < 4; ++s) {
      f16x8 a[4];
#pragma unroll
      for (int mi = 0; mi < 4; ++mi)
        a[mi] = *(const f16x8*)&As[(mrow + mi*16 + c) * LDA + s*32 + q*8];
#pragma unroll
      for (int ntl = 0; ntl < 2; ++ntl)
#pragma unroll
        for (int mi = 0; mi < 4; ++mi)
          u[mi][ntl] = __builtin_amdgcn_mfma_f32_16x16x32_f16(a[mi], b1f[s][ntl], u[mi][ntl], 0, 0, 0);
    }
    // GEMM2 B-frags BEFORE the store+barrier (8 frags = 32 VGPR)
    f16x8 b2f[2][4];
#pragma unroll
    for (int s2 = 0; s2 < 2; ++s2)
#pragma unroll
      for (int nt = 0; nt < 4; ++nt) {
        const int j2 = nw*4 + nt;
        b2f[s2][nt] = *(const f16x8*)&W2_pk[((size_t)(j2*8 + ch*2 + s2) * 64 + lane) * 8];
      }
#pragma unroll
    for (int ntl = 0; ntl < 2; ++ntl) {
      const int colg = ch*64 + nw*32 + ntl*16 + c;
      const float bb = b1[colg];
      const int coll = nw*32 + ntl*16 + c;
#pragma unroll
      for (int mi = 0; mi < 4; ++mi)
#pragma unroll
        for (int r = 0; r < 4; ++r)
          Us[(mrow + mi*16 + q*4 + r) * LDU + coll] = f2h(fmaxf(u[mi][ntl][r] + bb, 0.f));
    }
    __syncthreads();
#pragma unroll
    for (int s2 = 0; s2 < 2; ++s2) {
      f16x8 a2[4];
#pragma unroll
      for (int mi = 0; mi < 4; ++mi)
        a2[mi] = *(const f16x8*)&Us[(mrow + mi*16 + c) * LDU + s2*32 + q*8];
#pragma unroll
      for (int nt = 0; nt < 4; ++nt)
#pragma unroll
        for (int mi = 0; mi < 4; ++mi)
          h[mi][nt] = __builtin_amdgcn_mfma_f32_16x16x32_f16(a2[mi], b2f[s2][nt], h[mi][nt], 0, 0, 0);
    }
    __syncthreads();
  }
  if (b2) {
#pragma unroll
    for (int nt = 0; nt < 4; ++nt) {
      const float bb = b2[nw*64 + nt*16 + c];
#pragma unroll
      for (int mi = 0; mi < 4; ++mi) {
        h[mi][nt][0] += bb; h[mi][nt][1] += bb; h[mi][nt][2] += bb; h[mi][nt][3] += bb;
      }
    }
  }
}

// ---------------------------------------------------------------------------
// 64-row encoder (round-4 structure) + B-fragment register hoisting (round 6)
// + fp16 activations/weights (round 7).
// LDS 51200 B. launch_bounds(256,2): VGPR cap 256 — no spill. NOTE: (256,3)
// is infeasible here — unified VGPR+AGPR file counts the ~96 AGPR
// accumulators against the 170-reg 3-wave budget (rounds 1/2 spill).
// ---------------------------------------------------------------------------
#define LDA2 136
#define LDU2 264

struct Enc64Shared {
  unsigned short As[64 * LDA2];   // 17408 B
  unsigned short Us[64 * LDU2];   // 33792 B
};

__device__ __forceinline__ void mlp64(
    f32x4 (&h)[4][2], unsigned short* __restrict__ As, unsigned short* __restrict__ Us,
    const unsigned short* __restrict__ W1_pk, const float* __restrict__ b1,
    const unsigned short* __restrict__ W2_pk, const float* __restrict__ b2,
    int w, int c, int q, int lane)
{
  // GEMM1 B-frags upfront (16 frags = 64 VGPR): all independent loads in flight
  f16x8 b1f[4][4];
#pragma unroll
  for (int s = 0; s < 4; ++s)
#pragma unroll
    for (int ntl = 0; ntl < 4; ++ntl) {
      const int j = w*4 + ntl;
      b1f[s][ntl] = *(const f16x8*)&W1_pk[((size_t)(j*4 + s) * 64 + lane) * 8];
    }
  f32x4 u[4][4];
#pragma unroll
  for (int mi = 0; mi < 4; ++mi)
#pragma unroll
    for (int ntl = 0; ntl < 4; ++ntl) { f32x4 z = {0.f,0.f,0.f,0.f}; u[mi][ntl] = z; }
#pragma unroll
  for (int s = 0; s < 4; ++s) {
    f16x8 a[4];
#pragma unroll
    for (int mi = 0; mi < 4; ++mi)
      a[mi] = *(const f16x8*)&As[(mi*16 + c) * LDA2 + s*32 + q*8];
#pragma unroll
    for (int ntl = 0; ntl < 4; ++ntl)
#pragma unroll
      for (int mi = 0; mi < 4; ++mi)
        u[mi][ntl] = __builtin_amdgcn_mfma_f32_16x16x32_f16(a[mi], b1f[s][ntl], u[mi][ntl], 0, 0, 0);
  }
  // GEMM2 B-frags BEFORE the store+barrier: their L2 latency hides under it
  f16x8 b2f[8][2];
#pragma unroll
  for (int s2 = 0; s2 < 8; ++s2)
#pragma unroll
    for (int nt = 0; nt < 2; ++nt) {
      const int j2 = w*2 + nt;
      b2f[s2][nt] = *(const f16x8*)&W2_pk[((size_t)(j2*8 + s2) * 64 + lane) * 8];
    }
  // relu + bias -> full-width Us
#pragma unroll
  for (int ntl = 0; ntl < 4; ++ntl) {
    const int colg = w*64 + ntl*16 + c;
    const float bb = b1[colg];
#pragma unroll
    for (int mi = 0; mi < 4; ++mi)
#pragma unroll
      for (int r = 0; r < 4; ++r)
        Us[(mi*16 + q*4 + r) * LDU2 + colg] = f2h(fmaxf(u[mi][ntl][r] + bb, 0.f));
  }
  __syncthreads();
  // GEMM2: h += Us(64x256) @ W2(256x128), this wave: cols w*32..w*32+31
#pragma unroll
  for (int s2 = 0; s2 < 8; ++s2) {
    f16x8 a2[4];
#pragma unroll
    for (int mi = 0; mi < 4; ++mi)
      a2[mi] = *(const f16x8*)&Us[(mi*16 + c) * LDU2 + s2*32 + q*8];
#pragma unroll
    for (int nt = 0; nt < 2; ++nt)
#pragma unroll
      for (int mi = 0; mi < 4; ++mi)
        h[mi][nt] = __builtin_amdgcn_mfma_f32_16x16x32_f16(a2[mi], b2f[s2][nt], h[mi][nt], 0, 0, 0);
  }
  __syncthreads();
  if (b2) {
#pragma unroll
    for (int nt = 0; nt < 2; ++nt) {
      const float bb = b2[w*32 + nt*16 + c];
#pragma unroll
      for (int mi = 0; mi < 4; ++mi) {
        h[mi][nt][0] += bb; h[mi][nt][1] += bb; h[mi][nt][2] += bb; h[mi][nt][3] += bb;
      }
    }
  }
}

__device__ __forceinline__ void ln64(
    f32x4 (&h)[4][2], unsigned short* __restrict__ As, float* __restrict__ sc,
    const float* __restrict__ g, const float* __restrict__ bv,
    int w, int c, int q)
{
  float* lsum = sc;          // [4][64] overlay on Us
  float* lssq = sc + 256;    // [4][64]
  float ps[4][4], pss[4][4];
#pragma unroll
  for (int mi = 0; mi < 4; ++mi)
#pragma unroll
    for (int r = 0; r < 4; ++r) {
      float s = 0.f, ss = 0.f;
#pragma unroll
      for (int nt = 0; nt < 2; ++nt) { const float v = h[mi][nt][r]; s += v; ss += v * v; }
      ps[mi][r] = s; pss[mi][r] = ss;
    }
#pragma unroll
  for (int off = 1; off < 16; off <<= 1) {
#pragma unroll
    for (int mi = 0; mi < 4; ++mi)
#pragma unroll
      for (int r = 0; r < 4; ++r) {
        ps[mi][r] += __shfl_xor(ps[mi][r], off, 64);
        pss[mi][r] += __shfl_xor(pss[mi][r], off, 64);
      }
  }
#pragma unroll
  for (int r = 0; r < 4; ++r) {
    if (c == r) {
#pragma unroll
      for (int mi = 0; mi < 4; ++mi) {
        const int row = mi*16 + q*4 + r;
        lsum[w*64 + row] = ps[mi][r];
        lssq[w*64 + row] = pss[mi][r];
      }
    }
  }
  float gg[2], bb[2];
#pragma unroll
  for (int nt = 0; nt < 2; ++nt) {
    const int col = w*32 + nt*16 + c;
    gg[nt] = g[col]; bb[nt] = bv[col];
  }
  __syncthreads();
#pragma unroll
  for (int mi = 0; mi < 4; ++mi)
#pragma unroll
    for (int r = 0; r < 4; ++r) {
      const int row = mi*16 + q*4 + r;
      const float s  = lsum[row] + lsum[64 + row] + lsum[128 + row] + lsum[192 + row];
      const float ss = lssq[row] + lssq[64 + row] + lssq[128 + row] + lssq[192 + row];
      const float mu = s * (1.f / 128.f);
      const float rs = rsqrtf(ss * (1.f / 128.f) - mu * mu + LN_EPS);
#pragma unroll
      for (int nt = 0; nt < 2; ++nt) {
        const int col = w*32 + nt*16 + c;
        As[row * LDA2 + col] = f2h((h[mi][nt][r] - mu) * rs * gg[nt] + bb[nt]);
      }
    }
  __syncthreads();
}

__global__ __launch_bounds__(256, 2) void encode64(
    const float* __restrict__ cand_x, int N, int encC,
    const float* __restrict__ x_num, int B,
    const unsigned short* __restrict__ linW_pk, const float* __restrict__ lin_b,
    const unsigned short* __restrict__ e0W1_pk, const float* __restrict__ e0_b1,
    const unsigned short* __restrict__ e0W2_pk, const float* __restrict__ e0_b2,
    const float* __restrict__ e1_g, const float* __restrict__ e1_b,
    const unsigned short* __restrict__ e1W1_pk, const float* __restrict__ e1_b1,
    const unsigned short* __restrict__ e1W2_pk, const float* __restrict__ e1_b2,
    const float* __restrict__ mix_g, const float* __restrict__ mix_b,
    const unsigned short* __restrict__ KW_pk, const float* __restrict__ K_b,
    unsigned short* __restrict__ ckb, float* __restrict__ ckf,
    float* __restrict__ cknorm,
    float* __restrict__ xk, float* __restrict__ xh)
{
  __shared__ Enc64Shared sh;
  float* sc = (float*)sh.Us;
  const int t = threadIdx.x, lane = t & 63, w = t >> 6;
  const int c = lane & 15, q = lane >> 4;
  const bool isCand = (int)blockIdx.x < encC;
  const float* __restrict__ src = isCand ? cand_x : x_num;
  const int nrows = isCand ? N : B;
  const int row0 = (isCand ? (int)blockIdx.x : ((int)blockIdx.x - encC)) * 64;

  // stage 64 rows x 32 f32 -> f16 As[:, 0..31]
  for (int i = t; i < 64 * 8; i += 256) {
    const int r = i >> 3, c4 = (i & 7) * 4;
    const int gr = row0 + r;
    float4 v = make_float4(0.f, 0.f, 0.f, 0.f);
    if (gr < nrows) v = *(const float4*)&src[(size_t)gr * D_IN + c4];
    ushort4v u = {f2h(v.x), f2h(v.y), f2h(v.z), f2h(v.w)};
    *(ushort4v*)&sh.As[r * LDA2 + c4] = u;
  }
  __syncthreads();

  // input linear (K=32): h[4][2] covers cols w*32..w*32+31
  f32x4 h[4][2];
  {
    f16x8 bl[2];
#pragma unroll
    for (int nt = 0; nt < 2; ++nt)
      bl[nt] = *(const f16x8*)&linW_pk[((size_t)(w*2 + nt) * 64 + lane) * 8];
    f16x8 a[4];
#pragma unroll
    for (int mi = 0; mi < 4; ++mi)
      a[mi] = *(const f16x8*)&sh.As[(mi*16 + c) * LDA2 + q*8];
#pragma unroll
    for (int nt = 0; nt < 2; ++nt) {
      const float bb = lin_b[(w*2 + nt)*16 + c];
#pragma unroll
      for (int mi = 0; mi < 4; ++mi) {
        f32x4 z = {0.f, 0.f, 0.f, 0.f};
        z = __builtin_amdgcn_mfma_f32_16x16x32_f16(a[mi], bl[nt], z, 0, 0, 0);
        z[0] += bb; z[1] += bb; z[2] += bb; z[3] += bb;
        h[mi][nt] = z;
      }
    }
  }
  __syncthreads();
#pragma unroll
  for (int nt = 0; nt < 2; ++nt)
#pragma unroll
    for (int mi = 0; mi < 4; ++mi)
#pragma unroll
      for (int r = 0; r < 4; ++r)
        sh.As[(mi*16 + q*4 + r) * LDA2 + w*32 + nt*16 + c] = f2h(h[mi][nt][r]);
  __syncthreads();

  mlp64(h, sh.As, sh.Us, e0W1_pk, e0_b1, e0W2_pk, e0_b2, w, c, q, lane);
  ln64(h, sh.As, sc, e1_g, e1_b, w, c, q);
  mlp64(h, sh.As, sh.Us, e1W1_pk, e1_b1, e1W2_pk, e1_b2, w, c, q, lane);
  ln64(h, sh.As, sc, mix_g, mix_b, w, c, q);

  if (!isCand) {
    // write xh now so h is dead during the K-projection
#pragma unroll
    for (int nt = 0; nt < 2; ++nt) {
      const int col = w*32 + nt*16 + c;
#pragma unroll
      for (int mi = 0; mi < 4; ++mi)
#pragma unroll
        for (int r = 0; r < 4; ++r) {
          const int gr = row0 + mi*16 + q*4 + r;
          if (gr < nrows) xh[(size_t)gr * D_MAIN + col] = h[mi][nt][r];
        }
    }
  }

  // K projection: B-frags upfront (8 frags = 32 VGPR)
  f16x8 bk[4][2];
#pragma unroll
  for (int s = 0; s < 4; ++s)
#pragma unroll
    for (int nt = 0; nt < 2; ++nt) {
      const int j = w*2 + nt;
      bk[s][nt] = *(const f16x8*)&KW_pk[((size_t)(j*4 + s) * 64 + lane) * 8];
    }
  f32x4 kk[4][2];
#pragma unroll
  for (int mi = 0; mi < 4; ++mi)
#pragma unroll
    for (int nt = 0; nt < 2; ++nt) { f32x4 z = {0.f,0.f,0.f,0.f}; kk[mi][nt] = z; }
#pragma unroll
  for (int s = 0; s < 4; ++s) {
    f16x8 a[4];
#pragma unroll
    for (int mi = 0; mi < 4; ++mi)
      a[mi] = *(const f16x8*)&sh.As[(mi*16 + c) * LDA2 + s*32 + q*8];
#pragma unroll
    for (int nt = 0; nt < 2; ++nt)
#pragma unroll
      for (int mi = 0; mi < 4; ++mi)
        kk[mi][nt] = __builtin_amdgcn_mfma_f32_16x16x32_f16(a[mi], bk[s][nt], kk[mi][nt], 0, 0, 0);
  }

  if (isCand) {
#pragma unroll
    for (int nt = 0; nt < 2; ++nt) {
      const int col = w*32 + nt*16 + c;
      const float bb = K_b[col];
#pragma unroll
      for (int mi = 0; mi < 4; ++mi)
#pragma unroll
        for (int r = 0; r < 4; ++r) {
          const float v = kk[mi][nt][r] + bb;
          kk[mi][nt][r] = v;
          const int gr = row0 + mi*16 + q*4 + r;
          if (gr < nrows) {
            if (ckf) ckf[(size_t)gr * D_MAIN + col] = v;
            ckb[(size_t)gr * D_MAIN + col] = f2h(v);
          }
        }
    }
    // ||k||^2 per row -> sc overlay (Us free after mlp/ln barriers)
    float pss[4][4];
#pragma unroll
    for (int mi = 0; mi < 4; ++mi)
#pragma unroll
      for (int r = 0; r < 4; ++r) {
        float ss = 0.f;
#pragma unroll
        for (int nt = 0; nt < 2; ++nt) { const float v = kk[mi][nt][r]; ss += v * v; }
        pss[mi][r] = ss;
      }
#pragma unroll
    for (int off = 1; off < 16; off <<= 1)
#pragma unroll
      for (int mi = 0; mi < 4; ++mi)
#pragma unroll
        for (int r = 0; r < 4; ++r)
          pss[mi][r] += __shfl_xor(pss[mi][r], off, 64);
#pragma unroll
    for (int r = 0; r < 4; ++r) {
      if (c == r) {
#pragma unroll
        for (int mi = 0; mi < 4; ++mi)
          sc[w*64 + mi*16 + q*4 + r] = pss[mi][r];
      }
    }
    __syncthreads();
    if (t < 64) {
      const int gr = row0 + t;
      if (gr < nrows) cknorm[gr] = sc[t] + sc[64 + t] + sc[128 + t] + sc[192 + t];
    }
  } else {
#pragma unroll
    for (int nt = 0; nt < 2; ++nt) {
      const int col = w*32 + nt*16 + c;
      const float bb = K_b[col];
#pragma unroll
      for (int mi = 0; mi < 4; ++mi)
#pragma unroll
        for (int r = 0; r < 4; ++r) {
          const int gr = row0 + mi*16 + q*4 + r;
          if (gr < nrows) xk[(size_t)gr * D_MAIN + col] = kk[mi][nt][r] + bb;
        }
    }
  }
}

// ---------------------------------------------------------------------------
// Score: S[b][j] = 2*dot(xk[b], ck[j]) - ||ck[j]||^2, fp16.
// Round 8: S tile staged in LDS and written as 128B-contiguous lines per
// thread (old epilogue: 64 scalar 2B stores in 32B half-sector segments ->
// ~2x HBM write amplification on the 51MB S buffer).
// ---------------------------------------------------------------------------
__global__ __launch_bounds__(256) void score_mfma(
    const float* __restrict__ xk, const unsigned short* __restrict__ ckb,
    const float* __restrict__ cknorm, int N, int Npad,
    __half* __restrict__ S)
{
  __shared__ union {
    unsigned short Ks[64 * 136];   // 17408 B (phase 1)
    unsigned short St[64 * 264];   // 33792 B (phase 2; 264 pad keeps 16B align)
  } sh;
  const int t = threadIdx.x, lane = t & 63, w = t >> 6;
  const int c = lane & 15, q = lane >> 4;
  const int b0 = blockIdx.y * 64;
  const int nblk = blockIdx.x * 256;
  const int n0 = nblk + w * 64;

  f16x8 bf[4][4];
#pragma unroll
  for (int s = 0; s < 4; ++s)
#pragma unroll
    for (int nt = 0; nt < 4; ++nt) {
      const size_t n = (size_t)(n0 + nt*16 + c);
      bf[s][nt] = *(const f16x8*)&ckb[n * D_MAIN + s*32 + q*8];
    }

  for (int i = t; i < 64 * 32; i += 256) {
    const int r = i >> 5, c4 = (i & 31) * 4;
    const float4 v = *(const float4*)&xk[(size_t)(b0 + r) * D_MAIN + c4];
    ushort4v u = {f2h(v.x), f2h(v.y), f2h(v.z), f2h(v.w)};
    *(ushort4v*)&sh.Ks[r * 136 + c4] = u;
  }
  __syncthreads();

  f32x4 acc[4][4];
#pragma unroll
  for (int mi = 0; mi < 4; ++mi)
#pragma unroll
    for (int nt = 0; nt < 4; ++nt) { f32x4 z = {0.f,0.f,0.f,0.f}; acc[mi][nt] = z; }

#pragma unroll
  for (int s = 0; s < 4; ++s) {
    f16x8 a[4];
#pragma unroll
    for (int mi = 0; mi < 4; ++mi)
      a[mi] = *(const f16x8*)&sh.Ks[(mi*16 + c) * 136 + s*32 + q*8];
#pragma unroll
    for (int nt = 0; nt < 4; ++nt)
#pragma unroll
      for (int mi = 0; mi < 4; ++mi)
        acc[mi][nt] = __builtin_amdgcn_mfma_f32_16x16x32_f16(a[mi], bf[s][nt], acc[mi][nt], 0, 0, 0);
  }
  __syncthreads();   // all Ks reads complete before St overlays it

#pragma unroll
  for (int nt = 0; nt < 4; ++nt) {
    const int colin = w*64 + nt*16 + c;
    const int col = nblk + colin;
    const float cn = (col < N) ? cknorm[col] : 0.f;
#pragma unroll
    for (int mi = 0; mi < 4; ++mi)
#pragma unroll
      for (int r = 0; r < 4; ++r) {
        const float sv = (col < N) ? (2.f * acc[mi][nt][r] - cn) : -65504.f;
        sh.St[(mi*16 + q*4 + r) * 264 + colin] = f2h(sv);
      }
  }
  __syncthreads();
  {
    const int row = t >> 2, cb = (t & 3) * 64;   // 128B per thread, coalesced
    ushort8v* dst = (ushort8v*)(S + (size_t)(b0 + row) * Npad + nblk + cb);
#pragma unroll
    for (int i = 0; i < 8; ++i)
      dst[i] = *(const ushort8v*)&sh.St[row * 264 + cb + i*8];
  }
}

// ---------------------------------------------------------------------------
// Parallel radix-threshold top-K.
// Round 8: tthresh folded into tcollect (each block recomputes its row's
// threshold from ghist: 16KB L2 read + scan, removes one serial launch).
// ---------------------------------------------------------------------------
#define TK_CHUNK 12800
#define TK_RBINS 4096
#define TK_SCAP 2048

__device__ __forceinline__ unsigned flip2(unsigned u) {
  const unsigned m = (u >> 15) & 0x00010001u;
  const unsigned xm = (m * 0xFFFFu) | ((m ^ 0x00010001u) * 0x8000u);
  return u ^ xm;
}

__global__ __launch_bounds__(256) void thist_kernel(
    const __half* __restrict__ S, int Npad, int* __restrict__ ghist)
{
  __shared__ int lh[TK_RBINS];
  const int t = threadIdx.x;
  const int row = blockIdx.y;
  const int c0 = blockIdx.x * TK_CHUNK;
  const int jend = min(c0 + TK_CHUNK, Npad);
  for (int i = t; i < TK_RBINS; i += 256) lh[i] = 0;
  __syncthreads();
  const unsigned* rp = (const unsigned*)(S + (size_t)row * Npad);
  for (int j = c0 + t * 8; j < jend; j += 2048) {
    const uint4 v = *(const uint4*)(rp + (j >> 1));
    const unsigned k0 = flip2(v.x), k1 = flip2(v.y);
    const unsigned k2 = flip2(v.z), k3 = flip2(v.w);
    atomicAdd(&lh[(k0 & 0xFFFFu) >> 4], 1); atomicAdd(&lh[k0 >> 20], 1);
    atomicAdd(&lh[(k1 & 0xFFFFu) >> 4], 1); atomicAdd(&lh[k1 >> 20], 1);
    atomicAdd(&lh[(k2 & 0xFFFFu) >> 4], 1); atomicAdd(&lh[k2 >> 20], 1);
    atomicAdd(&lh[(k3 & 0xFFFFu) >> 4], 1); atomicAdd(&lh[k3 >> 20], 1);
  }
  __syncthreads();
  int* gh = ghist + (size_t)row * TK_RBINS;
  for (int i = t; i < TK_RBINS; i += 256) {
    const int v = lh[i];
    if (v) atomicAdd(&gh[i], v);
  }
}

__global__ __launch_bounds__(256) void tcollect_kernel(
    const __half* __restrict__ S, int Npad, const int* __restrict__ ghist,
    int* __restrict__ scount, unsigned long long* __restrict__ surv)
{
  __shared__ int sp[257];
  __shared__ int thrS;
  const int t = threadIdx.x;
  const int row = blockIdx.y;
  // --- inline per-row threshold from ghist (was tthresh kernel) ---
  const int* gh = ghist + (size_t)row * TK_RBINS;
  {
    int s = 0;
#pragma unroll
    for (int i = 0; i < 16; ++i) s += gh[t * 16 + i];
    sp[t] = s;
    if (t == 0) sp[256] = 0;
    __syncthreads();
    for (int off = 1; off < 256; off <<= 1) {
      const int v = (t + off < 256) ? sp[t + off] : 0;
      __syncthreads();
      sp[t] += v;
      __syncthreads();
    }
    if (sp[t] >= CTX && (t == 255 || sp[t + 1] < CTX)) {
      int running = (t == 255) ? 0 : sp[t + 1];
      int T = t * 16;
      for (int b = t * 16 + 15; b >= t * 16; --b) {
        running += gh[b];
        if (running >= CTX) { T = b; break; }
      }
      thrS = T;
    }
    __syncthreads();
  }
  const int T = thrS;
  const int c0 = blockIdx.x * TK_CHUNK;
  const int jend = min(c0 + TK_CHUNK, Npad);
  const unsigned* rp = (const unsigned*)(S + (size_t)row * Npad);
  unsigned long long* sv = surv + (size_t)row * TK_SCAP;
  for (int j = c0 + t * 8; j < jend; j += 2048) {
    const uint4 v = *(const uint4*)(rp + (j >> 1));
    unsigned ks[4] = {flip2(v.x), flip2(v.y), flip2(v.z), flip2(v.w)};
#pragma unroll
    for (int wqi = 0; wqi < 4; ++wqi) {
      const unsigned klo = ks[wqi] & 0xFFFFu;
      const unsigned khi = ks[wqi] >> 16;
      const int jlo = j + wqi * 2, jhi = j + wqi * 2 + 1;
      if ((int)(klo >> 4) >= T) {
        const int pos = atomicAdd(&scount[row], 1);
        if (pos < TK_SCAP)
          sv[pos] = ((unsigned long long)klo << 32) | (0xFFFFFFFFu - (unsigned)jlo);
      }
      if ((int)(khi >> 4) >= T) {
        const int pos = atomicAdd(&scount[row], 1);
        if (pos < TK_SCAP)
          sv[pos] = ((unsigned long long)khi << 32) | (0xFFFFFFFFu - (unsigned)jhi);
      }
    }
  }
}

__global__ __launch_bounds__(1024) void tsort_kernel(
    const unsigned long long* __restrict__ surv, const int* __restrict__ scount,
    int* __restrict__ idx_out)
{
  __shared__ unsigned long long sb[TK_SCAP];
  const int t = threadIdx.x;
  const int row = blockIdx.x;
  const int m = min(scount[row], TK_SCAP);
  int P = 128;
  while (P < m) P <<= 1;
  const unsigned long long* sv = surv + (size_t)row * TK_SCAP;
  for (int i = t; i < P; i += 1024)
    sb[i] = (i < m) ? sv[i] : 0x00000000FFFFFFFFull;
  __syncthreads();
  for (int k = 2; k <= P; k <<= 1) {
    for (int j = k >> 1; j > 0; j >>= 1) {
      for (int i = t; i < P; i += 1024) {
        const int ixj = i ^ j;
        if (ixj > i) {
          const unsigned long long a = sb[i], b = sb[ixj];
          const bool desc = ((i & k) == 0);
          if ((a < b) == desc) { sb[i] = b; sb[ixj] = a; }
        }
      }
      __syncthreads();
    }
  }
  if (t < CTX)
    idx_out[row * CTX + t] = (int)(0xFFFFFFFFu - (unsigned)(sb[t] & 0xFFFFFFFFu));
}

// ---------------------------------------------------------------------------
// T-module + predictor + head, MFMA. One block per query row, 4 waves.
// ---------------------------------------------------------------------------
struct TmodShared {
  unsigned short As[128 * LDA];
  unsigned short Us[128 * LDU];
  float part[2][128];
  float probs[128];
  float sims[128];
  float kb[128];
  float xhs[128];
  float ys[128];
  int   idxs[128];
  float ubuf[256];
  float vbuf[256];
  float xr[128];
  float dl[128];
  float scal[4];
};

__global__ __launch_bounds__(256, 2) void tmod_kernel(
    const float* __restrict__ xh, const float* __restrict__ xk,
    const unsigned short* __restrict__ ckb, const float* __restrict__ ckf,
    const float* __restrict__ cand_y, const int* __restrict__ ctx_idx,
    const unsigned short* __restrict__ TW1_pk, const float* __restrict__ T_b1,
    const unsigned short* __restrict__ TW2_pk,
    const float* __restrict__ lab_w, const float* __restrict__ lab_b,
    const float* __restrict__ p0_g, const float* __restrict__ p0_b,
    const float* __restrict__ p0_W1, const float* __restrict__ p0_b1,
    const float* __restrict__ p0_W2, const float* __restrict__ p0_b2,
    const float* __restrict__ head_g, const float* __restrict__ head_b,
    const float* __restrict__ head_W, const float* __restrict__ head_bias,
    float* __restrict__ out)
{
  __shared__ TmodShared sh;
  const int t = threadIdx.x, lane = t & 63, w = t >> 6;
  const int mw = w & 1, nw = w >> 1;
  const int c = lane & 15, q = lane >> 4;
  const int mrow = mw * 64;
  const int b = blockIdx.x;
  float* spart = (float*)sh.Us;   // [128][16], overlays Us (used pre-GEMM only)

  if (t < 128) {
    sh.ys[t] = 0.f;
    if (t < CTX) {
      const int j = ctx_idx[b * CTX + t];
      sh.idxs[t] = j;
      sh.ys[t] = cand_y[j];
    }
  }
  if (t < 32) {
    *(float4*)&sh.kb[t * 4] = *(const float4*)&xk[(size_t)b * D_MAIN + t * 4];
  } else if (t < 64) {
    const int i = t - 32;
    *(float4*)&sh.xhs[i * 4] = *(const float4*)&xh[(size_t)b * D_MAIN + i * 4];
  }
  __syncthreads();

  // stage diffs: row r (<96): diff = kb - ck[idx[r]]; f16 into As; ss -> spart
  for (int i = t; i < 128 * 16; i += 256) {
    const int r = i >> 4, seg = i & 15, c0 = seg * 8;
    if (r < CTX) {
      float v0x, v0y, v0z, v0w, v1x, v1y, v1z, v1w;
      if (ckf) {
        const float* cr = &ckf[(size_t)sh.idxs[r] * D_MAIN + c0];
        const float4 v0 = *(const float4*)cr;
        const float4 v1 = *(const float4*)(cr + 4);
        v0x = v0.x; v0y = v0.y; v0z = v0.z; v0w = v0.w;
        v1x = v1.x; v1y = v1.y; v1z = v1.z; v1w = v1.w;
      } else {
        const unsigned short* cr = &ckb[(size_t)sh.idxs[r] * D_MAIN + c0];
        const ushort4v u0 = *(const ushort4v*)cr;
        const ushort4v u1 = *(const ushort4v*)(cr + 4);
        v0x = h2f(u0[0]); v0y = h2f(u0[1]); v0z = h2f(u0[2]); v0w = h2f(u0[3]);
        v1x = h2f(u1[0]); v1y = h2f(u1[1]); v1z = h2f(u1[2]); v1w = h2f(u1[3]);
      }
      const float4 k0 = *(const float4*)&sh.kb[c0];
      const float4 k1 = *(const float4*)&sh.kb[c0 + 4];
      const float d0 = k0.x - v0x, d1 = k0.y - v0y, d2 = k0.z - v0z, d3 = k0.w - v0w;
      const float d4 = k1.x - v1x, d5 = k1.y - v1y, d6 = k1.z - v1z, d7 = k1.w - v1w;
      ushort4v u0s = {f2h(d0), f2h(d1), f2h(d2), f2h(d3)};
      ushort4v u1s = {f2h(d4), f2h(d5), f2h(d6), f2h(d7)};
      *(ushort4v*)&sh.As[r * LDA + c0] = u0s;
      *(ushort4v*)&sh.As[r * LDA + c0 + 4] = u1s;
      spart[r * 16 + seg] = d0*d0 + d1*d1 + d2*d2 + d3*d3 + d4*d4 + d5*d5 + d6*d6 + d7*d7;
    } else {
      ushort4v z = {0, 0, 0, 0};
      *(ushort4v*)&sh.As[r * LDA + c0] = z;
      *(ushort4v*)&sh.As[r * LDA + c0 + 4] = z;
    }
  }
  __syncthreads();
  if (t < 128) {
    float s = 0.f;
    if (t < CTX) {
#pragma unroll
      for (int seg = 0; seg < 16; ++seg) s += spart[t * 16 + seg];
      sh.sims[t] = -s;
    } else {
      sh.sims[t] = -FLT_MAX;
    }
  }
  __syncthreads();
  if (t < 64) {
    float m = fmaxf(sh.sims[t], sh.sims[t + 64]);
#pragma unroll
    for (int off = 32; off > 0; off >>= 1) m = fmaxf(m, __shfl_xor(m, off, 64));
    if (t == 0) sh.scal[0] = m;
  }
  __syncthreads();
  if (t < 128) {
    const float e = (t < CTX) ? __expf(sh.sims[t] - sh.scal[0]) : 0.f;
    sh.probs[t] = e;
  }
  __syncthreads();
  if (t < 64) {
    float s = sh.probs[t] + sh.probs[t + 64];
#pragma unroll
    for (int off = 32; off > 0; off >>= 1) s += __shfl_xor(s, off, 64);
    if (t == 0) sh.scal[1] = 1.f / s;
  }
  __syncthreads();
  if (t < 128) sh.probs[t] *= sh.scal[1];
  __syncthreads();
  if (t < 64) {
    float sy = sh.probs[t] * sh.ys[t] + sh.probs[t + 64] * sh.ys[t + 64];
#pragma unroll
    for (int off = 32; off > 0; off >>= 1) sy += __shfl_xor(sy, off, 64);
    if (t == 0) sh.scal[2] = sy;
  }
  __syncthreads();   // spart (Us) reads done; mlp_block may now write Us

  f32x4 h[4][4];
#pragma unroll
  for (int mi = 0; mi < 4; ++mi)
#pragma unroll
    for (int nt = 0; nt < 4; ++nt) { f32x4 z = {0.f,0.f,0.f,0.f}; h[mi][nt] = z; }
  mlp_block(h, sh.As, sh.Us, TW1_pk, T_b1, TW2_pk, nullptr, mrow, nw, c, q, lane);

  // weighted column reduction: ctx[col] = sum_rows probs[row] * h[row][col]
#pragma unroll
  for (int nt = 0; nt < 4; ++nt) {
    float p = 0.f;
#pragma unroll
    for (int mi = 0; mi < 4; ++mi)
#pragma unroll
      for (int r = 0; r < 4; ++r)
        p += sh.probs[mrow + mi*16 + q*4 + r] * h[mi][nt][r];
    p += __shfl_xor(p, 16, 64);
    p += __shfl_xor(p, 32, 64);
    if (q == 0) sh.part[mw][nw*64 + nt*16 + c] = p;
  }
  __syncthreads();

  if (t < 128)
    sh.xr[t] = sh.xhs[t] + sh.part[0][t] + sh.part[1][t] + sh.scal[2] * lab_w[t] + lab_b[t];
  __syncthreads();
  if (t < 64) {
    float s = sh.xr[t] + sh.xr[t + 64];
    float ss = sh.xr[t]*sh.xr[t] + sh.xr[t+64]*sh.xr[t+64];
#pragma unroll
    for (int off = 32; off > 0; off >>= 1) {
      s += __shfl_xor(s, off, 64);
      ss += __shfl_xor(ss, off, 64);
    }
    if (t == 0) {
      const float mu = s * (1.f / 128.f);
      sh.scal[0] = mu;
      sh.scal[1] = rsqrtf(ss * (1.f / 128.f) - mu * mu + LN_EPS);
    }
  }
  __syncthreads();
  if (t < 128)
    sh.dl[t] = (sh.xr[t] - sh.scal[0]) * sh.scal[1] * p0_g[t] + p0_b[t];
  __syncthreads();
  {
    float u = 0.f;
    for (int cc = 0; cc < D_MAIN; cc += 4) {
      const float w0 = p0_W1[(cc + 0) * D_BLOCK + t];
      const float w1 = p0_W1[(cc + 1) * D_BLOCK + t];
      const float w2 = p0_W1[(cc + 2) * D_BLOCK + t];
      const float w3 = p0_W1[(cc + 3) * D_BLOCK + t];
      const float4 d4 = *(const float4*)&sh.dl[cc];
      u += d4.x * w0 + d4.y * w1 + d4.z * w2 + d4.w * w3;
    }
    sh.ubuf[t] = fmaxf(u + p0_b1[t], 0.f);
  }
  __syncthreads();
  {
    const int cc = t & 127;
    const int d0 = (t >> 7) * 128;
    float v = 0.f;
    for (int d = d0; d < d0 + 128; d += 4) {
      const float w0 = p0_W2[(d + 0) * D_MAIN + cc];
      const float w1 = p0_W2[(d + 1) * D_MAIN + cc];
      const float w2 = p0_W2[(d + 2) * D_MAIN + cc];
      const float w3 = p0_W2[(d + 3) * D_MAIN + cc];
      const float4 u4 = *(const float4*)&sh.ubuf[d];
      v += u4.x * w0 + u4.y * w1 + u4.z * w2 + u4.w * w3;
    }
    sh.vbuf[t] = v;
  }
  __syncthreads();
  if (t < 128) sh.xr[t] += sh.vbuf[t] + sh.vbuf[t + 128] + p0_b2[t];
  __syncthreads();
  if (t < 64) {
    float s = sh.xr[t] + sh.xr[t + 64];
    float ss = sh.xr[t]*sh.xr[t] + sh.xr[t+64]*sh.xr[t+64];
#pragma unroll
    for (int off = 32; off > 0; off >>= 1) {
      s += __shfl_xor(s, off, 64);
      ss += __shfl_xor(ss, off, 64);
    }
    if (t == 0) {
      const float mu = s * (1.f / 128.f);
      sh.scal[0] = mu;
      sh.scal[1] = rsqrtf(ss * (1.f / 128.f) - mu * mu + LN_EPS);
    }
  }
  __syncthreads();
  if (t < 128) {
    float hv = (sh.xr[t] - sh.scal[0]) * sh.scal[1] * head_g[t] + head_b[t];
    sh.dl[t] = fmaxf(hv, 0.f) * head_W[t];
  }
  __syncthreads();
  if (t < 64) {
    float s = sh.dl[t] + sh.dl[t + 64];
#pragma unroll
    for (int off = 32; off > 0; off >>= 1) s += __shfl_xor(s, off, 64);
    if (t == 0) out[b] = s + head_bias[0];
  }
}

// ---------------------------------------------------------------------------
extern "C" void kernel_launch(void* const* d_in, const int* in_sizes, int n_in,
                              void* d_out, int out_size, void* d_ws, size_t ws_size,
                              hipStream_t stream)
{
  const float* x_num   = (const float*)d_in[0];
  const float* cand_x  = (const float*)d_in[1];
  const float* cand_y  = (const float*)d_in[2];
  const float* lin_W   = (const float*)d_in[4];
  const float* lin_b   = (const float*)d_in[5];
  const float* e0_W1   = (const float*)d_in[6];
  const float* e0_b1   = (const float*)d_in[7];
  const float* e0_W2   = (const float*)d_in[8];
  const float* e0_b2   = (const float*)d_in[9];
  const float* e1_g    = (const float*)d_in[10];
  const float* e1_b    = (const float*)d_in[11];
  const float* e1_W1   = (const float*)d_in[12];
  const float* e1_b1   = (const float*)d_in[13];
  const float* e1_W2   = (const float*)d_in[14];
  const float* e1_b2   = (const float*)d_in[15];
  const float* mix_g   = (const float*)d_in[16];
  const float* mix_b   = (const float*)d_in[17];
  const float* K_W     = (const float*)d_in[18];
  const float* K_b     = (const float*)d_in[19];
  const float* T_W1    = (const float*)d_in[20];
  const float* T_b1    = (const float*)d_in[21];
  const float* T_W2    = (const float*)d_in[22];
  const float* lab_w   = (const float*)d_in[23];
  const float* lab_b   = (const float*)d_in[24];
  const float* p0_g    = (const float*)d_in[25];
  const float* p0_b    = (const float*)d_in[26];
  const float* p0_W1   = (const float*)d_in[27];
  const float* p0_b1   = (const float*)d_in[28];
  const float* p0_W2   = (const float*)d_in[29];
  const float* p0_b2   = (const float*)d_in[30];
  const float* head_g  = (const float*)d_in[31];
  const float* head_b  = (const float*)d_in[32];
  const float* head_W  = (const float*)d_in[33];
  const float* head_bias = (const float*)d_in[34];
  float* out = (float*)d_out;

  const int N = in_sizes[1] / D_IN;
  const int B = in_sizes[0] / D_IN;
  const int Npad = ((N + 255) / 256) * 256;
  const int chunks = (Npad + TK_CHUNK - 1) / TK_CHUNK;

  char* p = (char*)d_ws;
  auto take = [&](size_t bytes) {
    char* q = p;
    p += (bytes + 255) & ~(size_t)255;
    return q;
  };
  unsigned short* pk_lin  = (unsigned short*)take(32  * 128 * 2);
  unsigned short* pk_e0w1 = (unsigned short*)take(128 * 256 * 2);
  unsigned short* pk_e0w2 = (unsigned short*)take(256 * 128 * 2);
  unsigned short* pk_e1w1 = (unsigned short*)take(128 * 256 * 2);
  unsigned short* pk_e1w2 = (unsigned short*)take(256 * 128 * 2);
  unsigned short* pk_kw   = (unsigned short*)take(128 * 128 * 2);
  unsigned short* pk_tw1  = (unsigned short*)take(128 * 256 * 2);
  unsigned short* pk_tw2  = (unsigned short*)take(256 * 128 * 2);
  unsigned short* ckb = (unsigned short*)take((size_t)Npad * D_MAIN * 2);
  float*  cknorm  = (float*)take((size_t)N * sizeof(float));
  float*  xh      = (float*)take((size_t)B * D_MAIN * sizeof(float));
  float*  xk      = (float*)take((size_t)B * D_MAIN * sizeof(float));
  __half* S       = (__half*)take((size_t)B * Npad * sizeof(__half));
  int*    ctxidx  = (int*)take((size_t)B * CTX * sizeof(int));
  int*    ghist   = (int*)take((size_t)B * TK_RBINS * sizeof(int));
  int*    scount  = (int*)take((size_t)B * sizeof(int));
  unsigned long long* surv =
      (unsigned long long*)take((size_t)B * TK_SCAP * sizeof(unsigned long long));
  // Optional f32 copy of candidate k (keeps tmod sims numerics exact).
  float* ckf = nullptr;
  {
    const size_t used = (size_t)(p - (char*)d_ws);
    const size_t need = (size_t)Npad * D_MAIN * sizeof(float);
    if (used + need + 256 <= ws_size) ckf = (float*)take(need);
  }
  (void)n_in; (void)out_size;

  // --- single prep launch: zero ghist/scount + pack all 8 weight matrices ---
  PackJobs pj;
  const float* ws_[8] = {lin_W, e0_W1, e0_W2, e1_W1, e1_W2, K_W, T_W1, T_W2};
  unsigned short* os_[8] = {pk_lin, pk_e0w1, pk_e0w2, pk_e1w1, pk_e1w2, pk_kw, pk_tw1, pk_tw2};
  const int Ks_[8] = {32, 128, 256, 128, 256, 128, 128, 256};
  const int Ns_[8] = {128, 256, 128, 256, 128, 128, 256, 128};
  pj.cum[0] = 0;
  for (int i = 0; i < 8; ++i) {
    pj.W[i] = ws_[i]; pj.out[i] = os_[i]; pj.K[i] = Ks_[i]; pj.N[i] = Ns_[i];
    pj.cum[i + 1] = pj.cum[i] + (Ns_[i] / 16) * (Ks_[i] / 32) * 64;
  }
  {
    const int na = B * TK_RBINS;
    const int total = (na + B > pj.cum[8]) ? (na + B) : pj.cum[8];
    prep_kernel<<<(total + 255) / 256, 256, 0, stream>>>(pj, ghist, na, scount, B);
  }

  // --- merged candidate + query encode, 64-row blocks ---
  const int encC = (N + 63) / 64;
  const int encB = (B + 63) / 64;
  encode64<<<encC + encB, 256, 0, stream>>>(
      cand_x, N, encC, x_num, B,
      pk_lin, lin_b, pk_e0w1, e0_b1, pk_e0w2, e0_b2,
      e1_g, e1_b, pk_e1w1, e1_b1, pk_e1w2, e1_b2,
      mix_g, mix_b, pk_kw, K_b,
      ckb, ckf, cknorm, xk, xh);

  dim3 sg(Npad / 256, B / 64);
  score_mfma<<<sg, 256, 0, stream>>>(xk, ckb, cknorm, N, Npad, S);

  dim3 tg(chunks, B);
  thist_kernel<<<tg, 256, 0, stream>>>(S, Npad, ghist);
  tcollect_kernel<<<tg, 256, 0, stream>>>(S, Npad, ghist, scount, surv);
  tsort_kernel<<<B, 1024, 0, stream>>>(surv, scount, ctxidx);

  tmod_kernel<<<B, 256, 0, stream>>>(
      xh, xk, ckb, ckf, cand_y, ctxidx,
      pk_tw1, T_b1, pk_tw2, lab_w, lab_b,
      p0_g, p0_b, p0_W1, p0_b1, p0_W2, p0_b2,
      head_g, head_b, head_W, head_bias, out);
}

// Round 9
// 330.466 us; speedup vs baseline: 1.0691x; 1.0691x over previous
//
#include <hip/hip_runtime.h>
#include <hip/hip_fp16.h>
#include <float.h>
#include <math.h>

#define D_IN 32
#define D_MAIN 128
#define D_BLOCK 256
#define CTX 96
#define LN_EPS 1e-5f

typedef _Float16 f16x8 __attribute__((ext_vector_type(8)));
typedef float f32x4 __attribute__((ext_vector_type(4)));
typedef unsigned short ushort4v __attribute__((ext_vector_type(4)));

// f32 -> f16 bits: single v_cvt_f16_f32 (RNE).
__device__ __forceinline__ unsigned short f2h(float x) {
  return __half_as_ushort(__float2half(x));
}
__device__ __forceinline__ float h2f(unsigned short u) {
  return __half2float(__ushort_as_half(u));
}

// ---------------------------------------------------------------------------
// Combined: zero ghist/scount + pack all 8 weight matrices (fp16, MFMA
// B-fragment order). frag f = j*(K/32)+s ; lane l holds
// B[k=32s+(l>>4)*8+jj][n=16j+(l&15)]
// ---------------------------------------------------------------------------
struct PackJobs {
  const float* W[8];
  unsigned short* out[8];
  int K[8];
  int N[8];
  int cum[9];
};

__global__ __launch_bounds__(256) void prep_kernel(
    PackJobs pj, int* __restrict__ ghist, int na, int* __restrict__ scount, int nb)
{
  const int tid = blockIdx.x * 256 + threadIdx.x;
  if (tid < na) ghist[tid] = 0;
  else if (tid - na < nb) scount[tid - na] = 0;
  if (tid >= pj.cum[8]) return;
  int j = 0;
#pragma unroll
  for (int i = 1; i < 8; ++i)
    if (tid >= pj.cum[i]) j = i;
  const int lt = tid - pj.cum[j];
  const int K = pj.K[j], N = pj.N[j];
  const float* __restrict__ W = pj.W[j];
  const int l = lt & 63, f = lt >> 6;
  const int ks = K / 32;
  const int s = f % ks, jb = f / ks;
  const int kb = s * 32 + (l >> 4) * 8;
  const int n = jb * 16 + (l & 15);
  unsigned short v[8];
#pragma unroll
  for (int e = 0; e < 8; ++e) v[e] = f2h(W[(size_t)(kb + e) * N + n]);
  ushort4v* o = (ushort4v*)(pj.out[j] + (size_t)lt * 8);
  ushort4v u0 = {v[0], v[1], v[2], v[3]};
  ushort4v u1 = {v[4], v[5], v[6], v[7]};
  o[0] = u0; o[1] = u1;
}

// ---------------------------------------------------------------------------
// 128-row MFMA MLP block — used by tmod only. B-fragments hoisted into
// registers (GEMM2's issued BEFORE the barrier so L2 latency hides under the
// Us store + barrier). tmod runs at cap 256 VGPR — no spill.
// ---------------------------------------------------------------------------
#define LDA 136
#define LDU 72

__device__ __forceinline__ void mlp_block(
    f32x4 (&h)[4][4], unsigned short* __restrict__ As, unsigned short* __restrict__ Us,
    const unsigned short* __restrict__ W1_pk, const float* __restrict__ b1,
    const unsigned short* __restrict__ W2_pk, const float* __restrict__ b2,
    int mrow, int nw, int c, int q, int lane)
{
#pragma unroll 1
  for (int ch = 0; ch < 4; ++ch) {
    // GEMM1 B-frags upfront (8 frags = 32 VGPR)
    f16x8 b1f[4][2];
#pragma unroll
    for (int s = 0; s < 4; ++s)
#pragma unroll
      for (int ntl = 0; ntl < 2; ++ntl) {
        const int j = ch*4 + nw*2 + ntl;
        b1f[s][ntl] = *(const f16x8*)&W1_pk[((size_t)(j*4 + s) * 64 + lane) * 8];
      }
    f32x4 u[4][2];
#pragma unroll
    for (int mi = 0; mi < 4; ++mi)
#pragma unroll
      for (int ntl = 0; ntl < 2; ++ntl) { f32x4 z = {0.f,0.f,0.f,0.f}; u[mi][ntl] = z; }
#pragma unroll
    for (int s = 0; s < 4; ++s) {
      f16x8 a[4];
#pragma unroll
      for (int mi = 0; mi < 4; ++mi)
        a[mi] = *(const f16x8*)&As[(mrow + mi*16 + c) * LDA + s*32 + q*8];
#pragma unroll
      for (int ntl = 0; ntl < 2; ++ntl)
#pragma unroll
        for (int mi = 0; mi < 4; ++mi)
          u[mi][ntl] = __builtin_amdgcn_mfma_f32_16x16x32_f16(a[mi], b1f[s][ntl], u[mi][ntl], 0, 0, 0);
    }
    // GEMM2 B-frags BEFORE the store+barrier (8 frags = 32 VGPR)
    f16x8 b2f[2][4];
#pragma unroll
    for (int s2 = 0; s2 < 2; ++s2)
#pragma unroll
      for (int nt = 0; nt < 4; ++nt) {
        const int j2 = nw*4 + nt;
        b2f[s2][nt] = *(const f16x8*)&W2_pk[((size_t)(j2*8 + ch*2 + s2) * 64 + lane) * 8];
      }
#pragma unroll
    for (int ntl = 0; ntl < 2; ++ntl) {
      const int colg = ch*64 + nw*32 + ntl*16 + c;
      const float bb = b1[colg];
      const int coll = nw*32 + ntl*16 + c;
#pragma unroll
      for (int mi = 0; mi < 4; ++mi)
#pragma unroll
        for (int r = 0; r < 4; ++r)
          Us[(mrow + mi*16 + q*4 + r) * LDU + coll] = f2h(fmaxf(u[mi][ntl][r] + bb, 0.f));
    }
    __syncthreads();
#pragma unroll
    for (int s2 = 0; s2 < 2; ++s2) {
      f16x8 a2[4];
#pragma unroll
      for (int mi = 0; mi < 4; ++mi)
        a2[mi] = *(const f16x8*)&Us[(mrow + mi*16 + c) * LDU + s2*32 + q*8];
#pragma unroll
      for (int nt = 0; nt < 4; ++nt)
#pragma unroll
        for (int mi = 0; mi < 4; ++mi)
          h[mi][nt] = __builtin_amdgcn_mfma_f32_16x16x32_f16(a2[mi], b2f[s2][nt], h[mi][nt], 0, 0, 0);
    }
    __syncthreads();
  }
  if (b2) {
#pragma unroll
    for (int nt = 0; nt < 4; ++nt) {
      const float bb = b2[nw*64 + nt*16 + c];
#pragma unroll
      for (int mi = 0; mi < 4; ++mi) {
        h[mi][nt][0] += bb; h[mi][nt][1] += bb; h[mi][nt][2] += bb; h[mi][nt][3] += bb;
      }
    }
  }
}

// ---------------------------------------------------------------------------
// 64-row encoder (round-4 structure) + B-fragment register hoisting (round 6)
// + fp16 activations/weights (round 7) + setprio around MFMA clusters
// (round 9: encode blocks are phase-staggered across a CU — the regime where
// setprio measured positive).
// LDS 51200 B. launch_bounds(256,2): VGPR cap 256 — no spill. NOTE: (256,3)
// is infeasible here — unified VGPR+AGPR file counts the accumulators
// against the 170-reg 3-wave budget (rounds 1/2 spill).
// ---------------------------------------------------------------------------
#define LDA2 136
#define LDU2 264

struct Enc64Shared {
  unsigned short As[64 * LDA2];   // 17408 B
  unsigned short Us[64 * LDU2];   // 33792 B
};

__device__ __forceinline__ void mlp64(
    f32x4 (&h)[4][2], unsigned short* __restrict__ As, unsigned short* __restrict__ Us,
    const unsigned short* __restrict__ W1_pk, const float* __restrict__ b1,
    const unsigned short* __restrict__ W2_pk, const float* __restrict__ b2,
    int w, int c, int q, int lane)
{
  // GEMM1 B-frags upfront (16 frags = 64 VGPR): all independent loads in flight
  f16x8 b1f[4][4];
#pragma unroll
  for (int s = 0; s < 4; ++s)
#pragma unroll
    for (int ntl = 0; ntl < 4; ++ntl) {
      const int j = w*4 + ntl;
      b1f[s][ntl] = *(const f16x8*)&W1_pk[((size_t)(j*4 + s) * 64 + lane) * 8];
    }
  f32x4 u[4][4];
#pragma unroll
  for (int mi = 0; mi < 4; ++mi)
#pragma unroll
    for (int ntl = 0; ntl < 4; ++ntl) { f32x4 z = {0.f,0.f,0.f,0.f}; u[mi][ntl] = z; }
  __builtin_amdgcn_s_setprio(1);
#pragma unroll
  for (int s = 0; s < 4; ++s) {
    f16x8 a[4];
#pragma unroll
    for (int mi = 0; mi < 4; ++mi)
      a[mi] = *(const f16x8*)&As[(mi*16 + c) * LDA2 + s*32 + q*8];
#pragma unroll
    for (int ntl = 0; ntl < 4; ++ntl)
#pragma unroll
      for (int mi = 0; mi < 4; ++mi)
        u[mi][ntl] = __builtin_amdgcn_mfma_f32_16x16x32_f16(a[mi], b1f[s][ntl], u[mi][ntl], 0, 0, 0);
  }
  __builtin_amdgcn_s_setprio(0);
  // GEMM2 B-frags BEFORE the store+barrier: their L2 latency hides under it
  f16x8 b2f[8][2];
#pragma unroll
  for (int s2 = 0; s2 < 8; ++s2)
#pragma unroll
    for (int nt = 0; nt < 2; ++nt) {
      const int j2 = w*2 + nt;
      b2f[s2][nt] = *(const f16x8*)&W2_pk[((size_t)(j2*8 + s2) * 64 + lane) * 8];
    }
  // relu + bias -> full-width Us
#pragma unroll
  for (int ntl = 0; ntl < 4; ++ntl) {
    const int colg = w*64 + ntl*16 + c;
    const float bb = b1[colg];
#pragma unroll
    for (int mi = 0; mi < 4; ++mi)
#pragma unroll
      for (int r = 0; r < 4; ++r)
        Us[(mi*16 + q*4 + r) * LDU2 + colg] = f2h(fmaxf(u[mi][ntl][r] + bb, 0.f));
  }
  __syncthreads();
  // GEMM2: h += Us(64x256) @ W2(256x128), this wave: cols w*32..w*32+31
  __builtin_amdgcn_s_setprio(1);
#pragma unroll
  for (int s2 = 0; s2 < 8; ++s2) {
    f16x8 a2[4];
#pragma unroll
    for (int mi = 0; mi < 4; ++mi)
      a2[mi] = *(const f16x8*)&Us[(mi*16 + c) * LDU2 + s2*32 + q*8];
#pragma unroll
    for (int nt = 0; nt < 2; ++nt)
#pragma unroll
      for (int mi = 0; mi < 4; ++mi)
        h[mi][nt] = __builtin_amdgcn_mfma_f32_16x16x32_f16(a2[mi], b2f[s2][nt], h[mi][nt], 0, 0, 0);
  }
  __builtin_amdgcn_s_setprio(0);
  __syncthreads();
  if (b2) {
#pragma unroll
    for (int nt = 0; nt < 2; ++nt) {
      const float bb = b2[w*32 + nt*16 + c];
#pragma unroll
      for (int mi = 0; mi < 4; ++mi) {
        h[mi][nt][0] += bb; h[mi][nt][1] += bb; h[mi][nt][2] += bb; h[mi][nt][3] += bb;
      }
    }
  }
}

__device__ __forceinline__ void ln64(
    f32x4 (&h)[4][2], unsigned short* __restrict__ As, float* __restrict__ sc,
    const float* __restrict__ g, const float* __restrict__ bv,
    int w, int c, int q)
{
  float* lsum = sc;          // [4][64] overlay on Us
  float* lssq = sc + 256;    // [4][64]
  float ps[4][4], pss[4][4];
#pragma unroll
  for (int mi = 0; mi < 4; ++mi)
#pragma unroll
    for (int r = 0; r < 4; ++r) {
      float s = 0.f, ss = 0.f;
#pragma unroll
      for (int nt = 0; nt < 2; ++nt) { const float v = h[mi][nt][r]; s += v; ss += v * v; }
      ps[mi][r] = s; pss[mi][r] = ss;
    }
#pragma unroll
  for (int off = 1; off < 16; off <<= 1) {
#pragma unroll
    for (int mi = 0; mi < 4; ++mi)
#pragma unroll
      for (int r = 0; r < 4; ++r) {
        ps[mi][r] += __shfl_xor(ps[mi][r], off, 64);
        pss[mi][r] += __shfl_xor(pss[mi][r], off, 64);
      }
  }
#pragma unroll
  for (int r = 0; r < 4; ++r) {
    if (c == r) {
#pragma unroll
      for (int mi = 0; mi < 4; ++mi) {
        const int row = mi*16 + q*4 + r;
        lsum[w*64 + row] = ps[mi][r];
        lssq[w*64 + row] = pss[mi][r];
      }
    }
  }
  float gg[2], bb[2];
#pragma unroll
  for (int nt = 0; nt < 2; ++nt) {
    const int col = w*32 + nt*16 + c;
    gg[nt] = g[col]; bb[nt] = bv[col];
  }
  __syncthreads();
#pragma unroll
  for (int mi = 0; mi < 4; ++mi)
#pragma unroll
    for (int r = 0; r < 4; ++r) {
      const int row = mi*16 + q*4 + r;
      const float s  = lsum[row] + lsum[64 + row] + lsum[128 + row] + lsum[192 + row];
      const float ss = lssq[row] + lssq[64 + row] + lssq[128 + row] + lssq[192 + row];
      const float mu = s * (1.f / 128.f);
      const float rs = rsqrtf(ss * (1.f / 128.f) - mu * mu + LN_EPS);
#pragma unroll
      for (int nt = 0; nt < 2; ++nt) {
        const int col = w*32 + nt*16 + c;
        As[row * LDA2 + col] = f2h((h[mi][nt][r] - mu) * rs * gg[nt] + bb[nt]);
      }
    }
  __syncthreads();
}

__global__ __launch_bounds__(256, 2) void encode64(
    const float* __restrict__ cand_x, int N, int encC,
    const float* __restrict__ x_num, int B,
    const unsigned short* __restrict__ linW_pk, const float* __restrict__ lin_b,
    const unsigned short* __restrict__ e0W1_pk, const float* __restrict__ e0_b1,
    const unsigned short* __restrict__ e0W2_pk, const float* __restrict__ e0_b2,
    const float* __restrict__ e1_g, const float* __restrict__ e1_b,
    const unsigned short* __restrict__ e1W1_pk, const float* __restrict__ e1_b1,
    const unsigned short* __restrict__ e1W2_pk, const float* __restrict__ e1_b2,
    const float* __restrict__ mix_g, const float* __restrict__ mix_b,
    const unsigned short* __restrict__ KW_pk, const float* __restrict__ K_b,
    unsigned short* __restrict__ ckb, float* __restrict__ cknorm,
    float* __restrict__ xk, float* __restrict__ xh)
{
  __shared__ Enc64Shared sh;
  float* sc = (float*)sh.Us;
  const int t = threadIdx.x, lane = t & 63, w = t >> 6;
  const int c = lane & 15, q = lane >> 4;
  const bool isCand = (int)blockIdx.x < encC;
  const float* __restrict__ src = isCand ? cand_x : x_num;
  const int nrows = isCand ? N : B;
  const int row0 = (isCand ? (int)blockIdx.x : ((int)blockIdx.x - encC)) * 64;

  // stage 64 rows x 32 f32 -> f16 As[:, 0..31]
  for (int i = t; i < 64 * 8; i += 256) {
    const int r = i >> 3, c4 = (i & 7) * 4;
    const int gr = row0 + r;
    float4 v = make_float4(0.f, 0.f, 0.f, 0.f);
    if (gr < nrows) v = *(const float4*)&src[(size_t)gr * D_IN + c4];
    ushort4v u = {f2h(v.x), f2h(v.y), f2h(v.z), f2h(v.w)};
    *(ushort4v*)&sh.As[r * LDA2 + c4] = u;
  }
  __syncthreads();

  // input linear (K=32): h[4][2] covers cols w*32..w*32+31
  f32x4 h[4][2];
  {
    f16x8 bl[2];
#pragma unroll
    for (int nt = 0; nt < 2; ++nt)
      bl[nt] = *(const f16x8*)&linW_pk[((size_t)(w*2 + nt) * 64 + lane) * 8];
    f16x8 a[4];
#pragma unroll
    for (int mi = 0; mi < 4; ++mi)
      a[mi] = *(const f16x8*)&sh.As[(mi*16 + c) * LDA2 + q*8];
#pragma unroll
    for (int nt = 0; nt < 2; ++nt) {
      const float bb = lin_b[(w*2 + nt)*16 + c];
#pragma unroll
      for (int mi = 0; mi < 4; ++mi) {
        f32x4 z = {0.f, 0.f, 0.f, 0.f};
        z = __builtin_amdgcn_mfma_f32_16x16x32_f16(a[mi], bl[nt], z, 0, 0, 0);
        z[0] += bb; z[1] += bb; z[2] += bb; z[3] += bb;
        h[mi][nt] = z;
      }
    }
  }
  __syncthreads();
#pragma unroll
  for (int nt = 0; nt < 2; ++nt)
#pragma unroll
    for (int mi = 0; mi < 4; ++mi)
#pragma unroll
      for (int r = 0; r < 4; ++r)
        sh.As[(mi*16 + q*4 + r) * LDA2 + w*32 + nt*16 + c] = f2h(h[mi][nt][r]);
  __syncthreads();

  mlp64(h, sh.As, sh.Us, e0W1_pk, e0_b1, e0W2_pk, e0_b2, w, c, q, lane);
  ln64(h, sh.As, sc, e1_g, e1_b, w, c, q);
  mlp64(h, sh.As, sh.Us, e1W1_pk, e1_b1, e1W2_pk, e1_b2, w, c, q, lane);
  ln64(h, sh.As, sc, mix_g, mix_b, w, c, q);

  if (!isCand) {
    // write xh now so h is dead during the K-projection
#pragma unroll
    for (int nt = 0; nt < 2; ++nt) {
      const int col = w*32 + nt*16 + c;
#pragma unroll
      for (int mi = 0; mi < 4; ++mi)
#pragma unroll
        for (int r = 0; r < 4; ++r) {
          const int gr = row0 + mi*16 + q*4 + r;
          if (gr < nrows) xh[(size_t)gr * D_MAIN + col] = h[mi][nt][r];
        }
    }
  }

  // K projection: B-frags upfront (8 frags = 32 VGPR)
  f16x8 bk[4][2];
#pragma unroll
  for (int s = 0; s < 4; ++s)
#pragma unroll
    for (int nt = 0; nt < 2; ++nt) {
      const int j = w*2 + nt;
      bk[s][nt] = *(const f16x8*)&KW_pk[((size_t)(j*4 + s) * 64 + lane) * 8];
    }
  f32x4 kk[4][2];
#pragma unroll
  for (int mi = 0; mi < 4; ++mi)
#pragma unroll
    for (int nt = 0; nt < 2; ++nt) { f32x4 z = {0.f,0.f,0.f,0.f}; kk[mi][nt] = z; }
  __builtin_amdgcn_s_setprio(1);
#pragma unroll
  for (int s = 0; s < 4; ++s) {
    f16x8 a[4];
#pragma unroll
    for (int mi = 0; mi < 4; ++mi)
      a[mi] = *(const f16x8*)&sh.As[(mi*16 + c) * LDA2 + s*32 + q*8];
#pragma unroll
    for (int nt = 0; nt < 2; ++nt)
#pragma unroll
      for (int mi = 0; mi < 4; ++mi)
        kk[mi][nt] = __builtin_amdgcn_mfma_f32_16x16x32_f16(a[mi], bk[s][nt], kk[mi][nt], 0, 0, 0);
  }
  __builtin_amdgcn_s_setprio(0);

  if (isCand) {
#pragma unroll
    for (int nt = 0; nt < 2; ++nt) {
      const int col = w*32 + nt*16 + c;
      const float bb = K_b[col];
#pragma unroll
      for (int mi = 0; mi < 4; ++mi)
#pragma unroll
        for (int r = 0; r < 4; ++r) {
          const float v = kk[mi][nt][r] + bb;
          kk[mi][nt][r] = v;
          const int gr = row0 + mi*16 + q*4 + r;
          if (gr < nrows) ckb[(size_t)gr * D_MAIN + col] = f2h(v);
        }
    }
    // ||k||^2 per row -> sc overlay (Us free after mlp/ln barriers)
    float pss[4][4];
#pragma unroll
    for (int mi = 0; mi < 4; ++mi)
#pragma unroll
      for (int r = 0; r < 4; ++r) {
        float ss = 0.f;
#pragma unroll
        for (int nt = 0; nt < 2; ++nt) { const float v = kk[mi][nt][r]; ss += v * v; }
        pss[mi][r] = ss;
      }
#pragma unroll
    for (int off = 1; off < 16; off <<= 1)
#pragma unroll
      for (int mi = 0; mi < 4; ++mi)
#pragma unroll
        for (int r = 0; r < 4; ++r)
          pss[mi][r] += __shfl_xor(pss[mi][r], off, 64);
#pragma unroll
    for (int r = 0; r < 4; ++r) {
      if (c == r) {
#pragma unroll
        for (int mi = 0; mi < 4; ++mi)
          sc[w*64 + mi*16 + q*4 + r] = pss[mi][r];
      }
    }
    __syncthreads();
    if (t < 64) {
      const int gr = row0 + t;
      if (gr < nrows) cknorm[gr] = sc[t] + sc[64 + t] + sc[128 + t] + sc[192 + t];
    }
  } else {
#pragma unroll
    for (int nt = 0; nt < 2; ++nt) {
      const int col = w*32 + nt*16 + c;
      const float bb = K_b[col];
#pragma unroll
      for (int mi = 0; mi < 4; ++mi)
#pragma unroll
        for (int r = 0; r < 4; ++r) {
          const int gr = row0 + mi*16 + q*4 + r;
          if (gr < nrows) xk[(size_t)gr * D_MAIN + col] = kk[mi][nt][r] + bb;
        }
    }
  }
}

// ---------------------------------------------------------------------------
// Score: S[b][j] = 2*dot(xk[b], ck[j]) - ||ck[j]||^2, fp16.
// ckb (fp16) B-frags hoisted before the Ks staging barrier. (Round-7 proven
// epilogue — round-8's LDS-staged store regressed.)
// ---------------------------------------------------------------------------
__global__ __launch_bounds__(256) void score_mfma(
    const float* __restrict__ xk, const unsigned short* __restrict__ ckb,
    const float* __restrict__ cknorm, int N, int Npad,
    __half* __restrict__ S)
{
  __shared__ unsigned short Ks[64 * 136];
  const int t = threadIdx.x, lane = t & 63, w = t >> 6;
  const int c = lane & 15, q = lane >> 4;
  const int b0 = blockIdx.y * 64;
  const int n0 = blockIdx.x * 256 + w * 64;

  f16x8 bf[4][4];
#pragma unroll
  for (int s = 0; s < 4; ++s)
#pragma unroll
    for (int nt = 0; nt < 4; ++nt) {
      const size_t n = (size_t)(n0 + nt*16 + c);
      bf[s][nt] = *(const f16x8*)&ckb[n * D_MAIN + s*32 + q*8];
    }

  for (int i = t; i < 64 * 32; i += 256) {
    const int r = i >> 5, c4 = (i & 31) * 4;
    const float4 v = *(const float4*)&xk[(size_t)(b0 + r) * D_MAIN + c4];
    ushort4v u = {f2h(v.x), f2h(v.y), f2h(v.z), f2h(v.w)};
    *(ushort4v*)&Ks[r * 136 + c4] = u;
  }
  __syncthreads();

  f32x4 acc[4][4];
#pragma unroll
  for (int mi = 0; mi < 4; ++mi)
#pragma unroll
    for (int nt = 0; nt < 4; ++nt) { f32x4 z = {0.f,0.f,0.f,0.f}; acc[mi][nt] = z; }

#pragma unroll
  for (int s = 0; s < 4; ++s) {
    f16x8 a[4];
#pragma unroll
    for (int mi = 0; mi < 4; ++mi)
      a[mi] = *(const f16x8*)&Ks[(mi*16 + c) * 136 + s*32 + q*8];
#pragma unroll
    for (int nt = 0; nt < 4; ++nt)
#pragma unroll
      for (int mi = 0; mi < 4; ++mi)
        acc[mi][nt] = __builtin_amdgcn_mfma_f32_16x16x32_f16(a[mi], bf[s][nt], acc[mi][nt], 0, 0, 0);
  }
#pragma unroll
  for (int nt = 0; nt < 4; ++nt) {
    const int col = n0 + nt*16 + c;
    const float cn = (col < N) ? cknorm[col] : 0.f;
#pragma unroll
    for (int mi = 0; mi < 4; ++mi)
#pragma unroll
      for (int r = 0; r < 4; ++r) {
        const int row = b0 + mi*16 + q*4 + r;
        const float sv = (col < N) ? (2.f * acc[mi][nt][r] - cn) : -65504.f;
        S[(size_t)row * Npad + col] = __float2half(sv);
      }
  }
}

// ---------------------------------------------------------------------------
// Parallel radix-threshold top-K (round-7 proven structure: separate
// tthresh — round-8's per-chunk-block threshold recompute regressed).
// ---------------------------------------------------------------------------
#define TK_CHUNK 12800
#define TK_RBINS 4096
#define TK_SCAP 2048

__device__ __forceinline__ unsigned flip2(unsigned u) {
  const unsigned m = (u >> 15) & 0x00010001u;
  const unsigned xm = (m * 0xFFFFu) | ((m ^ 0x00010001u) * 0x8000u);
  return u ^ xm;
}

__global__ __launch_bounds__(256) void thist_kernel(
    const __half* __restrict__ S, int Npad, int* __restrict__ ghist)
{
  __shared__ int lh[TK_RBINS];
  const int t = threadIdx.x;
  const int row = blockIdx.y;
  const int c0 = blockIdx.x * TK_CHUNK;
  const int jend = min(c0 + TK_CHUNK, Npad);
  for (int i = t; i < TK_RBINS; i += 256) lh[i] = 0;
  __syncthreads();
  const unsigned* rp = (const unsigned*)(S + (size_t)row * Npad);
  for (int j = c0 + t * 8; j < jend; j += 2048) {
    const uint4 v = *(const uint4*)(rp + (j >> 1));
    const unsigned k0 = flip2(v.x), k1 = flip2(v.y);
    const unsigned k2 = flip2(v.z), k3 = flip2(v.w);
    atomicAdd(&lh[(k0 & 0xFFFFu) >> 4], 1); atomicAdd(&lh[k0 >> 20], 1);
    atomicAdd(&lh[(k1 & 0xFFFFu) >> 4], 1); atomicAdd(&lh[k1 >> 20], 1);
    atomicAdd(&lh[(k2 & 0xFFFFu) >> 4], 1); atomicAdd(&lh[k2 >> 20], 1);
    atomicAdd(&lh[(k3 & 0xFFFFu) >> 4], 1); atomicAdd(&lh[k3 >> 20], 1);
  }
  __syncthreads();
  int* gh = ghist + (size_t)row * TK_RBINS;
  for (int i = t; i < TK_RBINS; i += 256) {
    const int v = lh[i];
    if (v) atomicAdd(&gh[i], v);
  }
}

__global__ __launch_bounds__(256) void tthresh_kernel(
    const int* __restrict__ ghist, int* __restrict__ thr)
{
  __shared__ int sp[257];
  const int t = threadIdx.x;
  const int row = blockIdx.x;
  const int* gh = ghist + (size_t)row * TK_RBINS;
  int s = 0;
#pragma unroll
  for (int i = 0; i < 16; ++i) s += gh[t * 16 + i];
  sp[t] = s;
  if (t == 0) sp[256] = 0;
  __syncthreads();
  for (int off = 1; off < 256; off <<= 1) {
    const int v = (t + off < 256) ? sp[t + off] : 0;
    __syncthreads();
    sp[t] += v;
    __syncthreads();
  }
  if (sp[t] >= CTX && (t == 255 || sp[t + 1] < CTX)) {
    int running = (t == 255) ? 0 : sp[t + 1];
    int T = t * 16;
    for (int b = t * 16 + 15; b >= t * 16; --b) {
      running += gh[b];
      if (running >= CTX) { T = b; break; }
    }
    thr[row] = T;
  }
}

__global__ __launch_bounds__(256) void tcollect_kernel(
    const __half* __restrict__ S, int Npad, const int* __restrict__ thr,
    int* __restrict__ scount, unsigned long long* __restrict__ surv)
{
  const int t = threadIdx.x;
  const int row = blockIdx.y;
  const int c0 = blockIdx.x * TK_CHUNK;
  const int jend = min(c0 + TK_CHUNK, Npad);
  const int T = thr[row];
  const unsigned* rp = (const unsigned*)(S + (size_t)row * Npad);
  unsigned long long* sv = surv + (size_t)row * TK_SCAP;
  for (int j = c0 + t * 8; j < jend; j += 2048) {
    const uint4 v = *(const uint4*)(rp + (j >> 1));
    unsigned ks[4] = {flip2(v.x), flip2(v.y), flip2(v.z), flip2(v.w)};
#pragma unroll
    for (int wqi = 0; wqi < 4; ++wqi) {
      const unsigned klo = ks[wqi] & 0xFFFFu;
      const unsigned khi = ks[wqi] >> 16;
      const int jlo = j + wqi * 2, jhi = j + wqi * 2 + 1;
      if ((int)(klo >> 4) >= T) {
        const int pos = atomicAdd(&scount[row], 1);
        if (pos < TK_SCAP)
          sv[pos] = ((unsigned long long)klo << 32) | (0xFFFFFFFFu - (unsigned)jlo);
      }
      if ((int)(khi >> 4) >= T) {
        const int pos = atomicAdd(&scount[row], 1);
        if (pos < TK_SCAP)
          sv[pos] = ((unsigned long long)khi << 32) | (0xFFFFFFFFu - (unsigned)jhi);
      }
    }
  }
}

__global__ __launch_bounds__(1024) void tsort_kernel(
    const unsigned long long* __restrict__ surv, const int* __restrict__ scount,
    int* __restrict__ idx_out)
{
  __shared__ unsigned long long sb[TK_SCAP];
  const int t = threadIdx.x;
  const int row = blockIdx.x;
  const int m = min(scount[row], TK_SCAP);
  int P = 128;
  while (P < m) P <<= 1;
  const unsigned long long* sv = surv + (size_t)row * TK_SCAP;
  for (int i = t; i < P; i += 1024)
    sb[i] = (i < m) ? sv[i] : 0x00000000FFFFFFFFull;
  __syncthreads();
  for (int k = 2; k <= P; k <<= 1) {
    for (int j = k >> 1; j > 0; j >>= 1) {
      for (int i = t; i < P; i += 1024) {
        const int ixj = i ^ j;
        if (ixj > i) {
          const unsigned long long a = sb[i], b = sb[ixj];
          const bool desc = ((i & k) == 0);
          if ((a < b) == desc) { sb[i] = b; sb[ixj] = a; }
        }
      }
      __syncthreads();
    }
  }
  if (t < CTX)
    idx_out[row * CTX + t] = (int)(0xFFFFFFFFu - (unsigned)(sb[t] & 0xFFFFFFFFu));
}

// ---------------------------------------------------------------------------
// T-module + predictor + head, MFMA. One block per query row, 4 waves.
// Round 9: reads candidate k as fp16 ckb (the f32 ckf copy is dropped —
// the diff is rounded to fp16 for the MFMA anyway).
// ---------------------------------------------------------------------------
struct TmodShared {
  unsigned short As[128 * LDA];
  unsigned short Us[128 * LDU];
  float part[2][128];
  float probs[128];
  float sims[128];
  float kb[128];
  float xhs[128];
  float ys[128];
  int   idxs[128];
  float ubuf[256];
  float vbuf[256];
  float xr[128];
  float dl[128];
  float scal[4];
};

__global__ __launch_bounds__(256, 2) void tmod_kernel(
    const float* __restrict__ xh, const float* __restrict__ xk,
    const unsigned short* __restrict__ ckb,
    const float* __restrict__ cand_y, const int* __restrict__ ctx_idx,
    const unsigned short* __restrict__ TW1_pk, const float* __restrict__ T_b1,
    const unsigned short* __restrict__ TW2_pk,
    const float* __restrict__ lab_w, const float* __restrict__ lab_b,
    const float* __restrict__ p0_g, const float* __restrict__ p0_b,
    const float* __restrict__ p0_W1, const float* __restrict__ p0_b1,
    const float* __restrict__ p0_W2, const float* __restrict__ p0_b2,
    const float* __restrict__ head_g, const float* __restrict__ head_b,
    const float* __restrict__ head_W, const float* __restrict__ head_bias,
    float* __restrict__ out)
{
  __shared__ TmodShared sh;
  const int t = threadIdx.x, lane = t & 63, w = t >> 6;
  const int mw = w & 1, nw = w >> 1;
  const int c = lane & 15, q = lane >> 4;
  const int mrow = mw * 64;
  const int b = blockIdx.x;
  float* spart = (float*)sh.Us;   // [128][16], overlays Us (used pre-GEMM only)

  if (t < 128) {
    sh.ys[t] = 0.f;
    if (t < CTX) {
      const int j = ctx_idx[b * CTX + t];
      sh.idxs[t] = j;
      sh.ys[t] = cand_y[j];
    }
  }
  if (t < 32) {
    *(float4*)&sh.kb[t * 4] = *(const float4*)&xk[(size_t)b * D_MAIN + t * 4];
  } else if (t < 64) {
    const int i = t - 32;
    *(float4*)&sh.xhs[i * 4] = *(const float4*)&xh[(size_t)b * D_MAIN + i * 4];
  }
  __syncthreads();

  // stage diffs: row r (<96): diff = kb - ck[idx[r]]; f16 into As; ss -> spart
  for (int i = t; i < 128 * 16; i += 256) {
    const int r = i >> 4, seg = i & 15, c0 = seg * 8;
    if (r < CTX) {
      const unsigned short* cr = &ckb[(size_t)sh.idxs[r] * D_MAIN + c0];
      const ushort4v u0 = *(const ushort4v*)cr;
      const ushort4v u1 = *(const ushort4v*)(cr + 4);
      const float v0x = h2f(u0[0]), v0y = h2f(u0[1]), v0z = h2f(u0[2]), v0w = h2f(u0[3]);
      const float v1x = h2f(u1[0]), v1y = h2f(u1[1]), v1z = h2f(u1[2]), v1w = h2f(u1[3]);
      const float4 k0 = *(const float4*)&sh.kb[c0];
      const float4 k1 = *(const float4*)&sh.kb[c0 + 4];
      const float d0 = k0.x - v0x, d1 = k0.y - v0y, d2 = k0.z - v0z, d3 = k0.w - v0w;
      const float d4 = k1.x - v1x, d5 = k1.y - v1y, d6 = k1.z - v1z, d7 = k1.w - v1w;
      ushort4v u0s = {f2h(d0), f2h(d1), f2h(d2), f2h(d3)};
      ushort4v u1s = {f2h(d4), f2h(d5), f2h(d6), f2h(d7)};
      *(ushort4v*)&sh.As[r * LDA + c0] = u0s;
      *(ushort4v*)&sh.As[r * LDA + c0 + 4] = u1s;
      spart[r * 16 + seg] = d0*d0 + d1*d1 + d2*d2 + d3*d3 + d4*d4 + d5*d5 + d6*d6 + d7*d7;
    } else {
      ushort4v z = {0, 0, 0, 0};
      *(ushort4v*)&sh.As[r * LDA + c0] = z;
      *(ushort4v*)&sh.As[r * LDA + c0 + 4] = z;
    }
  }
  __syncthreads();
  if (t < 128) {
    float s = 0.f;
    if (t < CTX) {
#pragma unroll
      for (int seg = 0; seg < 16; ++seg) s += spart[t * 16 + seg];
      sh.sims[t] = -s;
    } else {
      sh.sims[t] = -FLT_MAX;
    }
  }
  __syncthreads();
  if (t < 64) {
    float m = fmaxf(sh.sims[t], sh.sims[t + 64]);
#pragma unroll
    for (int off = 32; off > 0; off >>= 1) m = fmaxf(m, __shfl_xor(m, off, 64));
    if (t == 0) sh.scal[0] = m;
  }
  __syncthreads();
  if (t < 128) {
    const float e = (t < CTX) ? __expf(sh.sims[t] - sh.scal[0]) : 0.f;
    sh.probs[t] = e;
  }
  __syncthreads();
  if (t < 64) {
    float s = sh.probs[t] + sh.probs[t + 64];
#pragma unroll
    for (int off = 32; off > 0; off >>= 1) s += __shfl_xor(s, off, 64);
    if (t == 0) sh.scal[1] = 1.f / s;
  }
  __syncthreads();
  if (t < 128) sh.probs[t] *= sh.scal[1];
  __syncthreads();
  if (t < 64) {
    float sy = sh.probs[t] * sh.ys[t] + sh.probs[t + 64] * sh.ys[t + 64];
#pragma unroll
    for (int off = 32; off > 0; off >>= 1) sy += __shfl_xor(sy, off, 64);
    if (t == 0) sh.scal[2] = sy;
  }
  __syncthreads();   // spart (Us) reads done; mlp_block may now write Us

  f32x4 h[4][4];
#pragma unroll
  for (int mi = 0; mi < 4; ++mi)
#pragma unroll
    for (int nt = 0; nt < 4; ++nt) { f32x4 z = {0.f,0.f,0.f,0.f}; h[mi][nt] = z; }
  mlp_block(h, sh.As, sh.Us, TW1_pk, T_b1, TW2_pk, nullptr, mrow, nw, c, q, lane);

  // weighted column reduction: ctx[col] = sum_rows probs[row] * h[row][col]
#pragma unroll
  for (int nt = 0; nt < 4; ++nt) {
    float p = 0.f;
#pragma unroll
    for (int mi = 0; mi < 4; ++mi)
#pragma unroll
      for (int r = 0; r < 4; ++r)
        p += sh.probs[mrow + mi*16 + q*4 + r] * h[mi][nt][r];
    p += __shfl_xor(p, 16, 64);
    p += __shfl_xor(p, 32, 64);
    if (q == 0) sh.part[mw][nw*64 + nt*16 + c] = p;
  }
  __syncthreads();

  if (t < 128)
    sh.xr[t] = sh.xhs[t] + sh.part[0][t] + sh.part[1][t] + sh.scal[2] * lab_w[t] + lab_b[t];
  __syncthreads();
  if (t < 64) {
    float s = sh.xr[t] + sh.xr[t + 64];
    float ss = sh.xr[t]*sh.xr[t] + sh.xr[t+64]*sh.xr[t+64];
#pragma unroll
    for (int off = 32; off > 0; off >>= 1) {
      s += __shfl_xor(s, off, 64);
      ss += __shfl_xor(ss, off, 64);
    }
    if (t == 0) {
      const float mu = s * (1.f / 128.f);
      sh.scal[0] = mu;
      sh.scal[1] = rsqrtf(ss * (1.f / 128.f) - mu * mu + LN_EPS);
    }
  }
  __syncthreads();
  if (t < 128)
    sh.dl[t] = (sh.xr[t] - sh.scal[0]) * sh.scal[1] * p0_g[t] + p0_b[t];
  __syncthreads();
  {
    float u = 0.f;
    for (int cc = 0; cc < D_MAIN; cc += 4) {
      const float w0 = p0_W1[(cc + 0) * D_BLOCK + t];
      const float w1 = p0_W1[(cc + 1) * D_BLOCK + t];
      const float w2 = p0_W1[(cc + 2) * D_BLOCK + t];
      const float w3 = p0_W1[(cc + 3) * D_BLOCK + t];
      const float4 d4 = *(const float4*)&sh.dl[cc];
      u += d4.x * w0 + d4.y * w1 + d4.z * w2 + d4.w * w3;
    }
    sh.ubuf[t] = fmaxf(u + p0_b1[t], 0.f);
  }
  __syncthreads();
  {
    const int cc = t & 127;
    const int d0 = (t >> 7) * 128;
    float v = 0.f;
    for (int d = d0; d < d0 + 128; d += 4) {
      const float w0 = p0_W2[(d + 0) * D_MAIN + cc];
      const float w1 = p0_W2[(d + 1) * D_MAIN + cc];
      const float w2 = p0_W2[(d + 2) * D_MAIN + cc];
      const float w3 = p0_W2[(d + 3) * D_MAIN + cc];
      const float4 u4 = *(const float4*)&sh.ubuf[d];
      v += u4.x * w0 + u4.y * w1 + u4.z * w2 + u4.w * w3;
    }
    sh.vbuf[t] = v;
  }
  __syncthreads();
  if (t < 128) sh.xr[t] += sh.vbuf[t] + sh.vbuf[t + 128] + p0_b2[t];
  __syncthreads();
  if (t < 64) {
    float s = sh.xr[t] + sh.xr[t + 64];
    float ss = sh.xr[t]*sh.xr[t] + sh.xr[t+64]*sh.xr[t+64];
#pragma unroll
    for (int off = 32; off > 0; off >>= 1) {
      s += __shfl_xor(s, off, 64);
      ss += __shfl_xor(ss, off, 64);
    }
    if (t == 0) {
      const float mu = s * (1.f / 128.f);
      sh.scal[0] = mu;
      sh.scal[1] = rsqrtf(ss * (1.f / 128.f) - mu * mu + LN_EPS);
    }
  }
  __syncthreads();
  if (t < 128) {
    float hv = (sh.xr[t] - sh.scal[0]) * sh.scal[1] * head_g[t] + head_b[t];
    sh.dl[t] = fmaxf(hv, 0.f) * head_W[t];
  }
  __syncthreads();
  if (t < 64) {
    float s = sh.dl[t] + sh.dl[t + 64];
#pragma unroll
    for (int off = 32; off > 0; off >>= 1) s += __shfl_xor(s, off, 64);
    if (t == 0) out[b] = s + head_bias[0];
  }
}

// ---------------------------------------------------------------------------
extern "C" void kernel_launch(void* const* d_in, const int* in_sizes, int n_in,
                              void* d_out, int out_size, void* d_ws, size_t ws_size,
                              hipStream_t stream)
{
  const float* x_num   = (const float*)d_in[0];
  const float* cand_x  = (const float*)d_in[1];
  const float* cand_y  = (const float*)d_in[2];
  const float* lin_W   = (const float*)d_in[4];
  const float* lin_b   = (const float*)d_in[5];
  const float* e0_W1   = (const float*)d_in[6];
  const float* e0_b1   = (const float*)d_in[7];
  const float* e0_W2   = (const float*)d_in[8];
  const float* e0_b2   = (const float*)d_in[9];
  const float* e1_g    = (const float*)d_in[10];
  const float* e1_b    = (const float*)d_in[11];
  const float* e1_W1   = (const float*)d_in[12];
  const float* e1_b1   = (const float*)d_in[13];
  const float* e1_W2   = (const float*)d_in[14];
  const float* e1_b2   = (const float*)d_in[15];
  const float* mix_g   = (const float*)d_in[16];
  const float* mix_b   = (const float*)d_in[17];
  const float* K_W     = (const float*)d_in[18];
  const float* K_b     = (const float*)d_in[19];
  const float* T_W1    = (const float*)d_in[20];
  const float* T_b1    = (const float*)d_in[21];
  const float* T_W2    = (const float*)d_in[22];
  const float* lab_w   = (const float*)d_in[23];
  const float* lab_b   = (const float*)d_in[24];
  const float* p0_g    = (const float*)d_in[25];
  const float* p0_b    = (const float*)d_in[26];
  const float* p0_W1   = (const float*)d_in[27];
  const float* p0_b1   = (const float*)d_in[28];
  const float* p0_W2   = (const float*)d_in[29];
  const float* p0_b2   = (const float*)d_in[30];
  const float* head_g  = (const float*)d_in[31];
  const float* head_b  = (const float*)d_in[32];
  const float* head_W  = (const float*)d_in[33];
  const float* head_bias = (const float*)d_in[34];
  float* out = (float*)d_out;

  const int N = in_sizes[1] / D_IN;
  const int B = in_sizes[0] / D_IN;
  const int Npad = ((N + 255) / 256) * 256;
  const int chunks = (Npad + TK_CHUNK - 1) / TK_CHUNK;

  char* p = (char*)d_ws;
  auto take = [&](size_t bytes) {
    char* q = p;
    p += (bytes + 255) & ~(size_t)255;
    return q;
  };
  unsigned short* pk_lin  = (unsigned short*)take(32  * 128 * 2);
  unsigned short* pk_e0w1 = (unsigned short*)take(128 * 256 * 2);
  unsigned short* pk_e0w2 = (unsigned short*)take(256 * 128 * 2);
  unsigned short* pk_e1w1 = (unsigned short*)take(128 * 256 * 2);
  unsigned short* pk_e1w2 = (unsigned short*)take(256 * 128 * 2);
  unsigned short* pk_kw   = (unsigned short*)take(128 * 128 * 2);
  unsigned short* pk_tw1  = (unsigned short*)take(128 * 256 * 2);
  unsigned short* pk_tw2  = (unsigned short*)take(256 * 128 * 2);
  unsigned short* ckb = (unsigned short*)take((size_t)Npad * D_MAIN * 2);
  float*  cknorm  = (float*)take((size_t)N * sizeof(float));
  float*  xh      = (float*)take((size_t)B * D_MAIN * sizeof(float));
  float*  xk      = (float*)take((size_t)B * D_MAIN * sizeof(float));
  __half* S       = (__half*)take((size_t)B * Npad * sizeof(__half));
  int*    ctxidx  = (int*)take((size_t)B * CTX * sizeof(int));
  int*    ghist   = (int*)take((size_t)B * TK_RBINS * sizeof(int));
  int*    thr     = (int*)take((size_t)B * sizeof(int));
  int*    scount  = (int*)take((size_t)B * sizeof(int));
  unsigned long long* surv =
      (unsigned long long*)take((size_t)B * TK_SCAP * sizeof(unsigned long long));
  (void)n_in; (void)out_size; (void)ws_size;

  // --- single prep launch: zero ghist/scount + pack all 8 weight matrices ---
  PackJobs pj;
  const float* ws_[8] = {lin_W, e0_W1, e0_W2, e1_W1, e1_W2, K_W, T_W1, T_W2};
  unsigned short* os_[8] = {pk_lin, pk_e0w1, pk_e0w2, pk_e1w1, pk_e1w2, pk_kw, pk_tw1, pk_tw2};
  const int Ks_[8] = {32, 128, 256, 128, 256, 128, 128, 256};
  const int Ns_[8] = {128, 256, 128, 256, 128, 128, 256, 128};
  pj.cum[0] = 0;
  for (int i = 0; i < 8; ++i) {
    pj.W[i] = ws_[i]; pj.out[i] = os_[i]; pj.K[i] = Ks_[i]; pj.N[i] = Ns_[i];
    pj.cum[i + 1] = pj.cum[i] + (Ns_[i] / 16) * (Ks_[i] / 32) * 64;
  }
  {
    const int na = B * TK_RBINS;
    const int total = (na + B > pj.cum[8]) ? (na + B) : pj.cum[8];
    prep_kernel<<<(total + 255) / 256, 256, 0, stream>>>(pj, ghist, na, scount, B);
  }

  // --- merged candidate + query encode, 64-row blocks ---
  const int encC = (N + 63) / 64;
  const int encB = (B + 63) / 64;
  encode64<<<encC + encB, 256, 0, stream>>>(
      cand_x, N, encC, x_num, B,
      pk_lin, lin_b, pk_e0w1, e0_b1, pk_e0w2, e0_b2,
      e1_g, e1_b, pk_e1w1, e1_b1, pk_e1w2, e1_b2,
      mix_g, mix_b, pk_kw, K_b,
      ckb, cknorm, xk, xh);

  dim3 sg(Npad / 256, B / 64);
  score_mfma<<<sg, 256, 0, stream>>>(xk, ckb, cknorm, N, Npad, S);

  dim3 tg(chunks, B);
  thist_kernel<<<tg, 256, 0, stream>>>(S, Npad, ghist);
  tthresh_kernel<<<B, 256, 0, stream>>>(ghist, thr);
  tcollect_kernel<<<tg, 256, 0, stream>>>(S, Npad, thr, scount, surv);
  tsort_kernel<<<B, 1024, 0, stream>>>(surv, scount, ctxidx);

  tmod_kernel<<<B, 256, 0, stream>>>(
      xh, xk, ckb, cand_y, ctxidx,
      pk_tw1, T_b1, pk_tw2, lab_w, lab_b,
      p0_g, p0_b, p0_W1, p0_b1, p0_W2, p0_b2,
      head_g, head_b, head_W, head_bias, out);
}